// Round 8
// baseline (142.319 us; speedup 1.0000x reference)
//
#include <hip/hip_runtime.h>

// AnnularDilatedKNN: B=4, N=4096, C=64, SAMPLE=16, DILATED_RATE=2, r^2=256.
// Round 8: R7 query (branch-free ballot recording) + LDS-transpose gather:
//  - load: 16 lanes read one feature row contiguously (256 B coalesced),
//    scatter to channel-major LDS (stride 129 -> 2-way banks, free)
//  - store: half-wave per channel plane, dwordx4 stores (512 B contiguous)
// Numerics bit-match numpy: contract off, sq=(x*x+y*y)+z*z,
// dot=(xi*xj+yi*yj)+zi*zj, d2=(sqi+sqj)-2*dot.

#define BB 4
#define NN 4096
#define KK 16
#define PPB 8                   // points per block
#define NWORD 64                // 64-bit words per point (4096 bits)
#define MSTR 65                 // padded lmask row stride
#define TSTR 129                // smemT per-channel stride (floats)
#define PLANE (NN * KK)         // 65536

// ---------- K1: P[b*N+j] = (x, y, z, sq) ----------
__global__ __launch_bounds__(256)
void build_soa(const float* __restrict__ xyz, float4* __restrict__ P)
{
#pragma clang fp contract(off)
    const int g = blockIdx.x * 256 + threadIdx.x;      // 0..16383
    const float x = xyz[3 * g], y = xyz[3 * g + 1], z = xyz[3 * g + 2];
    const float sq = (x * x + y * y) + z * z;
    P[g] = make_float4(x, y, z, sq);
}

// ---------- K2: fused ballot query + extraction + transpose gather ----------
__global__ __launch_bounds__(256)
void query_gather(const float4* __restrict__ P, const float* __restrict__ feat,
                  float* __restrict__ out)
{
#pragma clang fp contract(off)
    __shared__ unsigned long long lmask[PPB * MSTR];   // 4.2 KB raw hit masks
    __shared__ int   sids[PPB * KK];                   // 128 ids
    __shared__ float smemT[64 * TSTR];                 // 33 KB channel-major tile

    const int blk  = blockIdx.x;            // 0..2047
    const int b    = blk >> 9;              // 512 blocks per batch
    const int i0   = (blk & 511) * PPB;     // first point (in batch)
    const int t    = threadIdx.x;
    const int lane = t & 63;
    const int wave = t >> 6;
    const int grp  = wave >> 1;             // 4-point group 0/1
    const int half = wave & 1;              // candidate half 0/1

    const float4* Pb = P + (b << 12);

    // ---- phase 1: record raw ballots, branch-free fixed loop ----
    {
        const int pb = i0 + grp * 4;
        const float4 pi0 = Pb[pb + 0];
        const float4 pi1 = Pb[pb + 1];
        const float4 pi2 = Pb[pb + 2];
        const float4 pi3 = Pb[pb + 3];
        const int jc0 = half * 32;          // first chunk of this wave's range

        float4 cur = Pb[(jc0 << 6) + lane];
        unsigned long long* lm = &lmask[(grp * 4) * MSTR + jc0];

        for (int c = 0; c < 32; ++c) {
            const float4 a = cur;
            cur = Pb[((jc0 + ((c + 1) & 31)) << 6) + lane];   // wrap prefetch

            const float dot0 = (pi0.x * a.x + pi0.y * a.y) + pi0.z * a.z;
            const float d20  = (pi0.w + a.w) - 2.0f * dot0;
            const float dot1 = (pi1.x * a.x + pi1.y * a.y) + pi1.z * a.z;
            const float d21  = (pi1.w + a.w) - 2.0f * dot1;
            const float dot2 = (pi2.x * a.x + pi2.y * a.y) + pi2.z * a.z;
            const float d22  = (pi2.w + a.w) - 2.0f * dot2;
            const float dot3 = (pi3.x * a.x + pi3.y * a.y) + pi3.z * a.z;
            const float d23  = (pi3.w + a.w) - 2.0f * dot3;

            const unsigned long long m0 = __ballot(d20 < 256.0f);
            const unsigned long long m1 = __ballot(d21 < 256.0f);
            const unsigned long long m2 = __ballot(d22 < 256.0f);
            const unsigned long long m3 = __ballot(d23 < 256.0f);

            if (lane == 0) {                // uniform values, single-lane store
                lm[c]            = m0;
                lm[c + MSTR]     = m1;
                lm[c + 2 * MSTR] = m2;
                lm[c + 3 * MSTR] = m3;
            }
        }
    }
    __syncthreads();

    // ---- phase 2: threads 0..7 extract rank 0 and ranks 16..30 for point t ----
    if (t < PPB) {
        const unsigned long long* mrow = &lmask[t * MSTR];
        int* row = sids + t * KK;
        int h0 = -1;
        int r  = 0;                          // hits consumed so far
        for (int w = 0; w < NWORD; ++w) {
            unsigned long long word = mrow[w];
            if (!word) continue;
            if (h0 < 0) h0 = (w << 6) + (int)__builtin_ctzll(word);
            const int c = __builtin_popcountll(word);
            if (r + c <= 16) { r += c; continue; }    // whole word below rank 16
            while (word) {
                const int bit = __builtin_ctzll(word);
                word &= word - 1;
                if (r >= 16) row[r - 15] = (w << 6) + bit;
                if (++r > 30) break;
            }
            if (r > 30) break;
        }
        row[0] = h0;                          // center slot (self-hit guarantees h0>=0)
        const int hi = (r < 31 ? r : 31) - 16;
        for (int s = (hi < 0 ? 1 : hi + 1); s <= 15; ++s) row[s] = h0;
    }
    __syncthreads();

    // ---- phase 3a: dilated_xyz (3 planes, 128 rows) + feature transpose-in ----
    if (t < PPB * KK) {                      // rows = pt*16 + k = t
        const int id = sids[t];
        const float4 p = Pb[id];
        float* o0 = out + (size_t)b * 3 * PLANE + i0 * KK + t;
        o0[0]         = p.x;
        o0[PLANE]     = p.y;
        o0[2 * PLANE] = p.z;
    }

    const float* fb = feat + ((size_t)b << 12) * 64;
#pragma unroll
    for (int it = 0; it < 8; ++it) {
        const int r  = it * 16 + (t >> 4);   // row 0..127
        const int c  = t & 15;               // float4 chunk within the row
        const int id = sids[r];
        const float4 v = reinterpret_cast<const float4*>(fb + (size_t)id * 64)[c];
        float* dst = &smemT[(4 * c) * TSTR + r];
        dst[0]        = v.x;                 // banks (4c+k+r)%32 -> 2-way, free
        dst[TSTR]     = v.y;
        dst[2 * TSTR] = v.z;
        dst[3 * TSTR] = v.w;
    }
    __syncthreads();

    // ---- phase 3b: write-out; half-wave per channel plane, dwordx4 stores ----
    const int h = t & 31;                    // covers rows 4h..4h+3
    float* o1 = out + (size_t)BB * 3 * PLANE + (size_t)b * 64 * PLANE + i0 * KK;
#pragma unroll
    for (int pp = 0; pp < 8; ++pp) {
        const int ch = pp * 8 + (t >> 5);
        const float* src = &smemT[ch * TSTR + 4 * h];
        const float4 v = make_float4(src[0], src[1], src[2], src[3]);
        *reinterpret_cast<float4*>(o1 + (size_t)ch * PLANE + 4 * h) = v;
    }
}

extern "C" void kernel_launch(void* const* d_in, const int* in_sizes, int n_in,
                              void* d_out, int out_size, void* d_ws, size_t ws_size,
                              hipStream_t stream) {
    const float* xyz  = (const float*)d_in[0];
    const float* feat = (const float*)d_in[1];
    float* out = (float*)d_out;

    float4* P = (float4*)d_ws;                       // 256 KB

    build_soa   <<<BB * NN / 256, 256, 0, stream>>>(xyz, P);
    query_gather<<<BB * NN / PPB, 256, 0, stream>>>(P, feat, out);   // 2048 blocks
}